// Round 8
// baseline (632.454 us; speedup 1.0000x reference)
//
#include <hip/hip_runtime.h>
#include <hip/hip_bf16.h>

#define M_DIM 8192
#define N_DIM 11008
#define K_DIM 4096
#define NT 32                        // K-tiles of BK=128 (int8)
#define RROW ((size_t)64 * K_DIM)    // 64 rows of int8, in bytes

typedef __attribute__((ext_vector_type(4))) int i32x4;

// ---------------- per-token activation quant: n = rint(x/s), s = max(absmax,1e-5)/7 ----------------
__global__ void quant_x_kernel(const float* __restrict__ x,
                               char* __restrict__ xq, float* __restrict__ sx) {
  const int row = blockIdx.x;      // 8192
  const int t = threadIdx.x;       // 256
  const float4* xr4 = (const float4*)(x + (size_t)row * K_DIM);
  float4 v[4];
  float amax = 0.0f;
#pragma unroll
  for (int i = 0; i < 4; ++i) {
    v[i] = xr4[t + 256 * i];
    amax = fmaxf(amax, fmaxf(fmaxf(fabsf(v[i].x), fabsf(v[i].y)),
                             fmaxf(fabsf(v[i].z), fabsf(v[i].w))));
  }
#pragma unroll
  for (int off = 32; off > 0; off >>= 1)
    amax = fmaxf(amax, __shfl_xor(amax, off, 64));
  __shared__ float red[4];
  if ((t & 63) == 0) red[t >> 6] = amax;
  __syncthreads();
  amax = fmaxf(fmaxf(red[0], red[1]), fmaxf(red[2], red[3]));
  const float s = fmaxf(amax, 1e-5f) / 7.0f;   // matches reference bitwise
  if (t == 0) sx[row] = s;
  char q[16];
#pragma unroll
  for (int i = 0; i < 4; ++i) {
    q[i * 4 + 0] = (char)(int)rintf(v[i].x / s);  // RNE, exact ints in [-7,7]
    q[i * 4 + 1] = (char)(int)rintf(v[i].y / s);
    q[i * 4 + 2] = (char)(int)rintf(v[i].z / s);
    q[i * 4 + 3] = (char)(int)rintf(v[i].w / s);
  }
  *(int4*)(xq + (size_t)row * K_DIM + t * 16) = *(int4*)q;
}

// ---------------- per-output-channel weight quant: int8 / 127 ----------------
__global__ void quant_w_kernel(const float* __restrict__ w,
                               char* __restrict__ wq, float* __restrict__ sw) {
  const int row = blockIdx.x;      // 11008
  const int t = threadIdx.x;       // 256
  const float4* wr4 = (const float4*)(w + (size_t)row * K_DIM);
  float4 v[4];
  float amax = 0.0f;
#pragma unroll
  for (int i = 0; i < 4; ++i) {
    v[i] = wr4[t + 256 * i];
    amax = fmaxf(amax, fmaxf(fmaxf(fabsf(v[i].x), fabsf(v[i].y)),
                             fmaxf(fabsf(v[i].z), fabsf(v[i].w))));
  }
#pragma unroll
  for (int off = 32; off > 0; off >>= 1)
    amax = fmaxf(amax, __shfl_xor(amax, off, 64));
  __shared__ float red[4];
  if ((t & 63) == 0) red[t >> 6] = amax;
  __syncthreads();
  amax = fmaxf(fmaxf(red[0], red[1]), fmaxf(red[2], red[3]));
  const float s = fmaxf(amax, 1e-30f) / 127.0f;
  if (t == 0) sw[row] = s;
  char q[16];
#pragma unroll
  for (int i = 0; i < 4; ++i) {
    q[i * 4 + 0] = (char)(int)rintf(v[i].x / s);  // in [-127,127]
    q[i * 4 + 1] = (char)(int)rintf(v[i].y / s);
    q[i * 4 + 2] = (char)(int)rintf(v[i].z / s);
    q[i * 4 + 3] = (char)(int)rintf(v[i].w / s);
  }
  *(int4*)(wq + (size_t)row * K_DIM + t * 16) = *(int4*)q;
}

// ---------------- GEMM ----------------
// 256x256 tile, BK=128 int8, 512 thr (8 waves 2x4). A-ONLY in LDS (64 KiB,
// dbuf, XOR-swizzled, 0 conflicts); B fragments load global->VGPR directly
// (16x64B segments, L2-resident via bm-fastest XCD swizzle). LDS traffic/tile
// drops 262->163 KB so the matrix pipe (2613 cyc) is the binding resource.
// No manual vmcnt: compiler-counted waits for B; __syncthreads drains staging.
#define GL(g, d)                                                             \
  __builtin_amdgcn_global_load_lds(                                          \
      (const __attribute__((address_space(1))) void*)(g),                    \
      (__attribute__((address_space(3))) void*)(d), 16, 0, 0)

#define MFMA_I8 __builtin_amdgcn_mfma_i32_16x16x64_i8

template<bool STG, bool PB>
__device__ __forceinline__ void tile(const char* pa, int colswz,
    const char* gAn, char* dA, const char* gBt,
    i32x4 (&bk0)[4], i32x4 (&bk1)[4], i32x4 (&acc)[8][4]) {
  __syncthreads();   // A(t) staged; prev buffer's readers done
  if constexpr (STG) {  // stage A(t+1) into the other buffer
    GL(gAn, dA);                GL(gAn + RROW, dA + 8192);
    GL(gAn + 2 * RROW, dA + 16384); GL(gAn + 3 * RROW, dA + 24576);
  }
  // B(t, k1) direct to regs
#pragma unroll
  for (int f = 0; f < 4; ++f)
    bk1[f] = *(const i32x4*)(gBt + 64 + (size_t)f * 16 * K_DIM);
  // k0: A from LDS, MFMA with bk0 (ready since before the barrier)
  i32x4 a[8];
#pragma unroll
  for (int f = 0; f < 8; ++f)
    a[f] = *(const i32x4*)(pa + f * 2048 + colswz);
#pragma unroll
  for (int m = 0; m < 8; ++m)
#pragma unroll
    for (int n = 0; n < 4; ++n)
      acc[m][n] = MFMA_I8(a[m], bk0[n], acc[m][n], 0, 0, 0);
  __builtin_amdgcn_sched_barrier(0);
  // prefetch B(t+1, k0) (bk0 regs free after the k0 MFMAs issue)
  if constexpr (PB) {
#pragma unroll
    for (int f = 0; f < 4; ++f)
      bk0[f] = *(const i32x4*)(gBt + 128 + (size_t)f * 16 * K_DIM);
  }
  // k1
#pragma unroll
  for (int f = 0; f < 8; ++f)
    a[f] = *(const i32x4*)(pa + f * 2048 + (colswz ^ 64));
#pragma unroll
  for (int m = 0; m < 8; ++m)
#pragma unroll
    for (int n = 0; n < 4; ++n)
      acc[m][n] = MFMA_I8(a[m], bk1[n], acc[m][n], 0, 0, 0);
}

__global__ __launch_bounds__(512, 2) void gemm_kernel(
    const char* __restrict__ xq, const char* __restrict__ wq,
    const float* __restrict__ sx, const float* __restrict__ sw,
    const float* __restrict__ bias, float* __restrict__ out) {
  __shared__ char lds_c[65536];  // A only: bufs 0/1 of 32 KiB

  const int tid = threadIdx.x;
  const int lane = tid & 63;
  const int wave = tid >> 6;
  const int wm = wave >> 2;       // 0..1
  const int wn = wave & 3;        // 0..3
  const int lr = lane & 15;

  // XCD swizzle, bm-fastest: the 32 concurrent blocks of an XCD share ~1
  // B-panel (1 MB << 4 MiB L2) -> direct B reads are L2-hot. Bijective:
  // 1376 = 8*172; sw = xcd*172 + i; bm = sw&31 (32 rows), bn = sw>>5 (43 cols).
  const int bid = blockIdx.x;
  const int sw_id = (bid & 7) * 172 + (bid >> 3);
  const int bm = sw_id & 31, bn = sw_id >> 5;
  const int m0 = bm * 256, n0 = bn * 256;

  // A staging source: thread t -> row tid>>3 (0..63), phys colbyte (tid&7)*16,
  // source colbyte = phys ^ ((row&7)<<4)   (inverse swizzle, rule #21)
  const int srow = tid >> 3;
  const int srccb = ((tid & 7) << 4) ^ ((srow & 7) << 4);
  const char* gA0 = xq + (size_t)(m0 + srow) * K_DIM + srccb;
  char* dA0 = lds_c + wave * 1024;            // wave-uniform; HW adds lane*16

  // A read base (swizzled): row = wm*128 + frag*16 + lr
  const int aRowOff = (wm * 128 + lr) * 128;
  const int colswz = ((lane >> 4) << 4) ^ ((lr & 7) << 4);

  // B direct base: row = n0 + wn*64 + frag*16 + lr, kbyte = (lane>>4)*16
  const char* gB0 = wq + (size_t)(n0 + wn * 64 + lr) * K_DIM + ((lane >> 4) << 4);

  i32x4 acc[8][4] = {};
  i32x4 bk0[4], bk1[4];

  // prologue: stage A(0) into buf 0; load B(0,k0)
  GL(gA0, dA0);                GL(gA0 + RROW, dA0 + 8192);
  GL(gA0 + 2 * RROW, dA0 + 16384); GL(gA0 + 3 * RROW, dA0 + 24576);
#pragma unroll
  for (int f = 0; f < 4; ++f)
    bk0[f] = *(const i32x4*)(gB0 + (size_t)f * 16 * K_DIM);

  for (int t = 0; t < NT - 1; ++t) {
    const int buf = t & 1;
    tile<true, true>(lds_c + buf * 32768 + aRowOff, colswz,
                     gA0 + (size_t)(t + 1) * 128, dA0 + (1 - buf) * 32768,
                     gB0 + (size_t)t * 128, bk0, bk1, acc);
  }
  tile<false, false>(lds_c + ((NT - 1) & 1) * 32768 + aRowOff, colswz,
                     nullptr, nullptr, gB0 + (size_t)(NT - 1) * 128, bk0, bk1, acc);

  // epilogue: C/D layout col=lane&15, row=(lane>>4)*4+reg (dtype-independent, m121/m128)
  const int orow0 = m0 + wm * 128 + (lane >> 4) * 4;
  const int ocol0 = n0 + wn * 64 + lr;
  float bv[4], swv[4];
#pragma unroll
  for (int fc = 0; fc < 4; ++fc) {
    bv[fc] = bias[ocol0 + fc * 16];
    swv[fc] = sw[ocol0 + fc * 16];
  }
#pragma unroll
  for (int fr = 0; fr < 8; ++fr) {
#pragma unroll
    for (int j = 0; j < 4; ++j) {
      const int grow = orow0 + fr * 16 + j;
      const float s = sx[grow];
      float* op = out + (size_t)grow * N_DIM + ocol0;
#pragma unroll
      for (int fc = 0; fc < 4; ++fc)
        op[fc * 16] = (float)acc[fr][fc][j] * (s * swv[fc]) + bv[fc];
    }
  }
}

extern "C" void kernel_launch(void* const* d_in, const int* in_sizes, int n_in,
                              void* d_out, int out_size, void* d_ws, size_t ws_size,
                              hipStream_t stream) {
  (void)in_sizes; (void)n_in; (void)out_size; (void)ws_size;
  const float* x = (const float*)d_in[0];       // [4,2048,4096] f32
  const float* w = (const float*)d_in[1];       // [11008,4096] f32
  const float* bias = (const float*)d_in[2];    // [1,11008] f32
  float* out = (float*)d_out;                   // [8192,11008] f32

  char* ws = (char*)d_ws;
  float* sx = (float*)ws;                                   // 32 KiB
  float* sw = (float*)(ws + 32768);                         // 44 KiB
  char* xq8 = ws + 131072;                                  // 32 MiB int8
  char* wq8 = ws + 131072 + (size_t)M_DIM * K_DIM;          // 43 MiB int8

  quant_x_kernel<<<M_DIM, 256, 0, stream>>>(x, xq8, sx);
  quant_w_kernel<<<N_DIM, 256, 0, stream>>>(w, wq8, sw);
  gemm_kernel<<<dim3((M_DIM / 256) * (N_DIM / 256)), 512, 0, stream>>>(xq8, wq8, sx, sw, bias, out);
}